// Round 1
// baseline (52.002 us; speedup 1.0000x reference)
//
#include <hip/hip_runtime.h>
#include <math.h>

#define B_SZ 4096
#define D_SZ 32
#define M1_SZ 8
#define H_SZ 64
#define NSTEP 20
#define S1 (NSTEP + 1)
#define BT 128

// Compute Clenshaw-Curtis weights + steps in double (matches numpy fp64 path).
__global__ void quad_init_kernel(float* __restrict__ quad) {
  int i = threadIdx.x;
  if (i < S1) {
    double acc = 0.0;
    for (int j = 0; j <= NSTEP; j += 2) {  // odd j have W[j]=0
      double wj = (j == 0) ? 1.0 : 2.0 / (1.0 - (double)j * (double)j);
      double l;
      if (i == 0)           l = 0.5;
      else if (i == NSTEP)  l = 0.5 * cos(M_PI * (double)j);
      else                  l = cos(M_PI * (double)(j * i) / (double)NSTEP);
      acc += l * wj * (2.0 / (double)NSTEP);
    }
    quad[i] = (float)acc;                                   // cc_weights[i]
    quad[S1 + i] = (float)cos(M_PI * (double)i / (double)NSTEP);  // steps[i]
  }
}

__global__ __launch_bounds__(BT) void umnn_main_kernel(
    const float* __restrict__ x, const float* __restrict__ x0,
    const float* __restrict__ We, const float* __restrict__ be,
    const float* __restrict__ W1, const float* __restrict__ b1,
    const float* __restrict__ W2, const float* __restrict__ b2,
    const float* __restrict__ scaling, const float* __restrict__ quad,
    float* __restrict__ out) {
  const int d = blockIdx.x;            // 0..31
  const int btile = blockIdx.y * BT;   // batch tile start
  const int tid = threadIdx.x;

  __shared__ float W1s[(M1_SZ + 1) * H_SZ];  // W1[d, i, h], i-major
  __shared__ float b1s[H_SZ];
  __shared__ float W2s[H_SZ];
  __shared__ float Wes[M1_SZ * D_SZ];        // We rows m*32+d
  __shared__ float bes[M1_SZ];
  __shared__ float ccws[S1];
  __shared__ float stepss[S1];
  __shared__ float misc[2];                  // b2[d], exp(scaling[d])
  __shared__ float xs[BT * (D_SZ + 1)];      // x tile, +1 pad vs bank conflicts

  for (int i = tid; i < (M1_SZ + 1) * H_SZ; i += BT)
    W1s[i] = W1[d * (M1_SZ + 1) * H_SZ + i];
  if (tid < H_SZ) { b1s[tid] = b1[d * H_SZ + tid]; W2s[tid] = W2[d * H_SZ + tid]; }
  if (tid < M1_SZ) bes[tid] = be[tid * D_SZ + d];
  for (int i = tid; i < M1_SZ * D_SZ; i += BT) {
    int m = i >> 5, c = i & 31;
    Wes[i] = We[(m * D_SZ + d) * D_SZ + c];
  }
  if (tid < S1) { ccws[tid] = quad[tid]; stepss[tid] = quad[S1 + tid]; }
  if (tid == 0) { misc[0] = b2[d]; misc[1] = __expf(scaling[d]); }
  for (int i = tid; i < BT * D_SZ; i += BT) {
    int r = i >> 5, c = i & 31;
    xs[r * (D_SZ + 1) + c] = x[(size_t)btile * D_SZ + i];  // coalesced
  }
  __syncthreads();

  const int b = btile + tid;
  const float* xrow = &xs[tid * (D_SZ + 1)];

  // --- masked encoder: h[b,m,d] = tanh(sum_{c<d} x[b,c]*We[m*32+d,c] + be) ---
  float a[M1_SZ];
#pragma unroll
  for (int m = 0; m < M1_SZ; ++m) a[m] = bes[m];
  for (int c = 0; c < d; ++c) {
    float xc = xrow[c];
#pragma unroll
    for (int m = 0; m < M1_SZ; ++m) a[m] = fmaf(xc, Wes[m * D_SZ + c], a[m]);
  }
  float hm[M1_SZ];
#pragma unroll
  for (int m = 0; m < M1_SZ; ++m) hm[m] = tanhf(a[m]);

  const float xb = xrow[d];
  const float x0b = x0[(size_t)b * D_SZ + d];
  const float dxe = xb - x0b;
  const float xc0 = x0b + 0.5f * dxe;  // X_s = xc0 + xc1*steps[s]
  const float xc1 = 0.5f * dxe;

  float Xs[S1];
#pragma unroll
  for (int s = 0; s < S1; ++s) Xs[s] = fmaf(xc1, stepss[s], xc0);

  const float b2v = misc[0];
  float acc[S1];  // accumulates hid·W2 per step, init with b2
#pragma unroll
  for (int s = 0; s < S1; ++s) acc[s] = b2v;

  // --- MLP over H, all 21 steps at once; base[h] hoisted out of s-loop ---
#pragma unroll 2
  for (int hh = 0; hh < H_SZ; ++hh) {
    float w1x = W1s[hh];           // W1[d,0,h] (multiplies X_s)
    float base = b1s[hh];
#pragma unroll
    for (int m = 0; m < M1_SZ; ++m)
      base = fmaf(hm[m], W1s[(m + 1) * H_SZ + hh], base);
    float w2h = W2s[hh];
#pragma unroll
    for (int s = 0; s < S1; ++s) {
      float pre = fmaf(Xs[s], w1x, base);
      float e = pre > 0.f ? pre : __expf(pre) - 1.f;  // elu
      acc[s] = fmaf(e, w2h, acc[s]);
    }
  }

  float dzsum = 0.f;
#pragma unroll
  for (int s = 0; s < S1; ++s) {
    float p = acc[s];
    float dz = (p > 0.f ? p : __expf(p) - 1.f) + 1.f;  // elu + 1
    dzsum = fmaf(ccws[s], dz, dzsum);
  }

  float z = fmaf(0.5f * dxe, dzsum, hm[0]);  // z_int + z0
  out[(size_t)b * D_SZ + d] = misc[1] * z;
}

extern "C" void kernel_launch(void* const* d_in, const int* in_sizes, int n_in,
                              void* d_out, int out_size, void* d_ws, size_t ws_size,
                              hipStream_t stream) {
  const float* x       = (const float*)d_in[0];
  const float* x0      = (const float*)d_in[1];
  const float* We      = (const float*)d_in[2];
  const float* be      = (const float*)d_in[3];
  const float* W1      = (const float*)d_in[4];
  const float* b1      = (const float*)d_in[5];
  const float* W2      = (const float*)d_in[6];
  const float* b2      = (const float*)d_in[7];
  const float* scaling = (const float*)d_in[8];
  float* quad = (float*)d_ws;   // 42 floats
  float* out  = (float*)d_out;

  quad_init_kernel<<<1, 64, 0, stream>>>(quad);
  dim3 grid(D_SZ, B_SZ / BT);
  umnn_main_kernel<<<grid, BT, 0, stream>>>(x, x0, We, be, W1, b1, W2, b2,
                                            scaling, quad, out);
}

// Round 2
// 44.810 us; speedup vs baseline: 1.1605x; 1.1605x over previous
//
#include <hip/hip_runtime.h>
#include <math.h>

#define B_SZ 4096
#define D_SZ 32
#define M1_SZ 8
#define H_SZ 64
#define NSTEP 20
#define S1 21
#define BROWS 64   // batch rows per block
#define BT 256     // threads: 4 waves; lane = [q(2b)|b_lo(4b)], wave supplies 16 rows
#define HQ 16      // h values per thread (64 / 4 quarters)

#ifndef M_PI
#define M_PI 3.14159265358979323846
#endif

#define LOG2E 1.44269504088896340736f
#define LN2   0.69314718055994530942f

__device__ __forceinline__ float fast_exp2(float x) {
#if __has_builtin(__builtin_amdgcn_exp2f)
  return __builtin_amdgcn_exp2f(x);
#else
  return exp2f(x);
#endif
}

__device__ __forceinline__ float fast_rcp(float x) {
#if __has_builtin(__builtin_amdgcn_rcpf)
  return __builtin_amdgcn_rcpf(x);
#else
  return 1.0f / x;
#endif
}

__global__ __launch_bounds__(BT) void umnn_main_kernel(
    const float* __restrict__ x, const float* __restrict__ x0,
    const float* __restrict__ We, const float* __restrict__ be,
    const float* __restrict__ W1, const float* __restrict__ b1,
    const float* __restrict__ W2, const float* __restrict__ b2,
    const float* __restrict__ scaling, float* __restrict__ out) {
  const int btile = blockIdx.x * BROWS;
  const int d = blockIdx.y;  // 0..31, uniform per block
  const int tid = threadIdx.x;

  __shared__ float W1s[(M1_SZ + 1) * H_SZ];  // [i][h], i-major (576)
  __shared__ float b1s[H_SZ];
  __shared__ float W2s[H_SZ];
  __shared__ float Wes[D_SZ * M1_SZ];  // c-major: [c][m] to spread banks
  __shared__ float bes[M1_SZ];
  __shared__ float ccws[S1];
  __shared__ float stepss[S1];
  __shared__ float misc[2];            // b2[d], exp(scaling[d])
  __shared__ float xs[BROWS * 36];     // x tile, row stride 36 (16B-aligned, bank-spread)

  // ---- staging ----
  {
    const float* W1d = W1 + d * (M1_SZ + 1) * H_SZ;
    for (int i = tid; i < (M1_SZ + 1) * H_SZ; i += BT) W1s[i] = W1d[i];
    if (tid < H_SZ) { b1s[tid] = b1[d * H_SZ + tid]; W2s[tid] = W2[d * H_SZ + tid]; }
    if (tid < M1_SZ) bes[tid] = be[tid * D_SZ + d];
    {  // We rows m*32+d, stored c-major
      int m = tid >> 5, c = tid & 31;
      Wes[c * M1_SZ + m] = We[(m * D_SZ + d) * D_SZ + c];
    }
    // x tile: 2048 floats = 512 float4; row stride 36 floats in LDS
    const float4* xg = reinterpret_cast<const float4*>(x + (size_t)btile * D_SZ);
#pragma unroll
    for (int k = 0; k < 2; ++k) {
      int i4 = tid + k * BT;          // 0..511
      int row = i4 >> 3, c4 = i4 & 7; // 8 float4 per 32-float row
      *reinterpret_cast<float4*>(&xs[row * 36 + c4 * 4]) = xg[i4];
    }
    if (tid < S1) {  // Clenshaw-Curtis weights + steps (fp32; threshold is lenient)
      stepss[tid] = cosf((float)tid * ((float)M_PI / 20.f));
      float acc = 0.f;
#pragma unroll
      for (int k = 0; k <= 10; ++k) {
        float w = (k == 0) ? 1.f : 2.f / (1.f - 4.f * (float)(k * k));
        float c = cosf((float)(k * tid) * ((float)M_PI / 10.f));
        float lam = (tid == 0 || tid == NSTEP) ? 0.5f * c : c;
        acc += w * lam;
      }
      ccws[tid] = 0.1f * acc;  // * 2/nb_steps
    }
    if (tid == 0) { misc[0] = b2[d]; misc[1] = __expf(scaling[d]); }
  }
  __syncthreads();

  const int lane = tid & 63;
  const int q = lane >> 4;                          // h-quarter 0..3
  const int b_local = ((tid >> 6) << 4) | (lane & 15);
  const int b = btile + b_local;
  const float* xrow = &xs[b_local * 36];

  // ---- masked encoder: hm[m] = tanh(sum_{c<d} x[c]*We[m*32+d,c] + be[m]) ----
  float a[M1_SZ];
#pragma unroll
  for (int m = 0; m < M1_SZ; ++m) a[m] = bes[m];
  for (int c = 0; c < d; ++c) {  // wave-uniform trip count
    float xc = xrow[c];
#pragma unroll
    for (int m = 0; m < M1_SZ; ++m) a[m] = fmaf(xc, Wes[c * M1_SZ + m], a[m]);
  }
  float hm[M1_SZ];
#pragma unroll
  for (int m = 0; m < M1_SZ; ++m) {  // tanh(x) = 1 - 2/(exp2(2x*log2e)+1)
    float t = fast_exp2(a[m] * (2.f * LOG2E));
    hm[m] = 1.f - 2.f * fast_rcp(t + 1.f);
  }

  // ---- quadrature points in log2 domain ----
  const float xb = xrow[d];
  const float x0b = x0[(size_t)b * D_SZ + d];
  const float dxe = xb - x0b;
  const float xc1 = 0.5f * dxe;
  const float xc1L = xc1 * LOG2E;
  const float xc0L = (x0b + xc1) * LOG2E;
  float XsL[S1];
#pragma unroll
  for (int s = 0; s < S1; ++s) XsL[s] = fmaf(xc1L, stepss[s], xc0L);

  // ---- per-quarter accumulators; fold (-1)*w2 of elu into init ----
  float w2sum = 0.f;
#pragma unroll
  for (int hi = 0; hi < HQ; ++hi) w2sum += W2s[q * HQ + hi];
  const float acc0 = (q == 0 ? misc[0] : 0.f) - w2sum;
  float acc[S1];
#pragma unroll
  for (int s = 0; s < S1; ++s) acc[s] = acc0;

  // ---- main loop: my 16 h's × 21 steps ----
#pragma unroll 2
  for (int hi = 0; hi < HQ; ++hi) {
    const int hh = q * HQ + hi;
    float base = b1s[hh];
#pragma unroll
    for (int m = 0; m < M1_SZ; ++m)
      base = fmaf(hm[m], W1s[(m + 1) * H_SZ + hh], base);
    const float baseL = base * LOG2E;
    const float w1x = W1s[hh];   // W1[d,0,h] (coefficient of X_s)
    const float w2h = W2s[hh];
#pragma unroll
    for (int s = 0; s < S1; ++s) {
      float preL = fmaf(XsL[s], w1x, baseL);
      float mn = fminf(preL, 0.f);
      float mx = fmaxf(preL, 0.f);
      float e = fmaf(mx, LN2, fast_exp2(mn));  // elu(pre)+1
      acc[s] = fmaf(e, w2h, acc[s]);
    }
  }

  // ---- reduce the 4 h-quarters (butterfly over lane bits 4,5) ----
#pragma unroll
  for (int s = 0; s < S1; ++s) {
    acc[s] += __shfl_xor(acc[s], 16);
    acc[s] += __shfl_xor(acc[s], 32);
  }

  // ---- second elu + quadrature sum (redundant across q; no divergence) ----
  float dzsum = 0.f;
#pragma unroll
  for (int s = 0; s < S1; ++s) {
    float pL = acc[s] * LOG2E;
    // elu(p)+1 = max(p,0) + exp(min(p,0))
    float dz = fmaf(fmaxf(pL, 0.f), LN2, fast_exp2(fminf(pL, 0.f)));
    dzsum = fmaf(ccws[s], dz, dzsum);
  }

  float z = fmaf(xc1, dzsum, hm[0]);  // z_int + z0
  if (q == 0) out[(size_t)b * D_SZ + d] = misc[1] * z;
}

extern "C" void kernel_launch(void* const* d_in, const int* in_sizes, int n_in,
                              void* d_out, int out_size, void* d_ws, size_t ws_size,
                              hipStream_t stream) {
  const float* x       = (const float*)d_in[0];
  const float* x0      = (const float*)d_in[1];
  const float* We      = (const float*)d_in[2];
  const float* be      = (const float*)d_in[3];
  const float* W1      = (const float*)d_in[4];
  const float* b1      = (const float*)d_in[5];
  const float* W2      = (const float*)d_in[6];
  const float* b2      = (const float*)d_in[7];
  const float* scaling = (const float*)d_in[8];
  float* out = (float*)d_out;

  dim3 grid(B_SZ / BROWS, D_SZ);
  umnn_main_kernel<<<grid, BT, 0, stream>>>(x, x0, We, be, W1, b1, W2, b2,
                                            scaling, out);
}